// Round 10
// baseline (285.351 us; speedup 1.0000x reference)
//
#include <hip/hip_runtime.h>
#include <hip/hip_bf16.h>
#include <math.h>

#define B 64
#define N 512
#define C 1024
#define K_NEIGH 32
// Band half-width: need DELTA - bisect_window/2 - E' > E', where
// E' = E_gemm + E_store. E_gemm ~ 0.15 (9-sigma fp16-hi GEMM error);
// E_store <= 0.07 (fp16 storage rounding for band-relevant |v| <= 256).
// max window = 2800/2^12 = 0.68 -> DELTA > 0.34 + 0.44 = 0.78; DELTA = 0.9.
// (tight-bracket path: window 20/2^5 = 0.625 -> even stricter separation)
// Non-band elements are strictly separated from the true rank-32 cut;
// band candidates are exactly rechecked in fp32 (bitwise-matching dots).
#define DELTA 0.9f
#define BISECT_ITERS 12

typedef __attribute__((ext_vector_type(8))) _Float16 half8;
typedef __attribute__((ext_vector_type(4))) float f32x4;

__device__ __forceinline__ half8 cvt8(float4 a, float4 b) {
    half8 g;
    g[0] = (_Float16)a.x; g[1] = (_Float16)a.y; g[2] = (_Float16)a.z; g[3] = (_Float16)a.w;
    g[4] = (_Float16)b.x; g[5] = (_Float16)b.y; g[6] = (_Float16)b.z; g[7] = (_Float16)b.w;
    return g;
}

// ---------------------------------------------------------------------------
// Kernel 1: S16[b] = fp16( fp16(x[b]) * fp16(x[b])^T ) via f16 MFMA.
// EXACT r6/r7 version (best measured: 77us). 256x256 tile, 512 thr = 8 waves
// (2x4, wave tile 128x64), BK=32, rotated 2-phase pipeline, raw barrier
// (vmcnt NOT drained). r9's BK=64 regressed (87us: barrier count is not the
// cost; per-iter staging latency is) -- reverted.
// ---------------------------------------------------------------------------
__global__ __launch_bounds__(512, 2) void gemm_f16(const float* __restrict__ x,
                                                   _Float16* __restrict__ S16) {
    __shared__ half8 Ah[2][1024];   // 2 x 16KB (4 granule-cols x 256 rows)
    __shared__ half8 Bh[2][1024];   // 2 x 16KB

    const int id   = blockIdx.x;           // 0..255
    const int xcd  = id & 7;
    const int slot = id >> 3;              // 0..31
    const int b    = xcd * 8 + (slot >> 2);
    const int tile = slot & 3;
    const int ti = tile >> 1, tj = tile & 1;
    const int row0 = ti * 256;
    const int col0 = tj * 256;
    const float* xb = x + (size_t)b * N * C;
    const bool diag = (ti == tj);

    const int t    = threadIdx.x;
    const int w    = t >> 6;
    const int lane = t & 63;
    const int quad = lane >> 4;
    const int lid  = lane & 15;
    const int wr   = (w >> 2) * 128;       // 2 wave-rows of 128
    const int wc   = (w & 3) * 64;         // 4 wave-cols of 64

    const int srow = t >> 1;
    const int s0   = (t & 1) * 2;
    const int koff = (t & 1) * 16;

    f32x4 acc[8][4];
#pragma unroll
    for (int r = 0; r < 8; r++)
#pragma unroll
        for (int c = 0; c < 4; c++)
#pragma unroll
            for (int e = 0; e < 4; e++) acc[r][c][e] = 0.f;

    const float* pArow = xb + (size_t)(row0 + srow) * C + koff;
    const float* pBrow = xb + (size_t)(col0 + srow) * C + koff;

    float4 ra[4], rb[4];
    {
        const float4* pa = (const float4*)pArow;
#pragma unroll
        for (int i = 0; i < 4; i++) ra[i] = pa[i];
        if (!diag) {
            const float4* pb = (const float4*)pBrow;
#pragma unroll
            for (int i = 0; i < 4; i++) rb[i] = pb[i];
        }
    }

    const int NIT = C / 32;                 // 32 K-steps
    for (int it = 0; it < NIT; ++it) {
        const int p = it & 1;
        Ah[p][s0 * 256 + srow]       = cvt8(ra[0], ra[1]);
        Ah[p][(s0 + 1) * 256 + srow] = cvt8(ra[2], ra[3]);
        if (!diag) {
            Bh[p][s0 * 256 + srow]       = cvt8(rb[0], rb[1]);
            Bh[p][(s0 + 1) * 256 + srow] = cvt8(rb[2], rb[3]);
        }
        if (it + 1 < NIT) {
            const float4* pa = (const float4*)(pArow + (it + 1) * 32);
#pragma unroll
            for (int i = 0; i < 4; i++) ra[i] = pa[i];
            if (!diag) {
                const float4* pb = (const float4*)(pBrow + (it + 1) * 32);
#pragma unroll
                for (int i = 0; i < 4; i++) rb[i] = pb[i];
            }
        }
        asm volatile("s_waitcnt lgkmcnt(0)" ::: "memory");
        __builtin_amdgcn_s_barrier();
        const half8* Ab = &Ah[p][0];
        const half8* Bb = diag ? Ab : &Bh[p][0];
        half8 vb[4];
#pragma unroll
        for (int c = 0; c < 4; c++) vb[c] = Bb[quad * 256 + wc + c * 16 + lid];
        __builtin_amdgcn_s_setprio(1);
#pragma unroll
        for (int r = 0; r < 8; r++) {
            half8 va = Ab[quad * 256 + wr + r * 16 + lid];
#pragma unroll
            for (int c = 0; c < 4; c++)
                acc[r][c] = __builtin_amdgcn_mfma_f32_16x16x32_f16(va, vb[c], acc[r][c], 0, 0, 0);
        }
        __builtin_amdgcn_s_setprio(0);
    }

    _Float16* Sb = S16 + (size_t)b * N * N;
#pragma unroll
    for (int r = 0; r < 8; r++) {
#pragma unroll
        for (int c = 0; c < 4; c++) {
#pragma unroll
            for (int e = 0; e < 4; e++) {
                const int grow = row0 + wr + r * 16 + quad * 4 + e;
                const int gcol = col0 + wc + c * 16 + lid;
                Sb[(size_t)grow * N + gcol] = (_Float16)acc[r][c][e];
            }
        }
    }
}

// ---------------------------------------------------------------------------
// Per-row threshold logic (exact r7 chain): sigma bracket -> checked 5-iter
// bisection (12-iter wide fallback) -> band scan -> wave-cooperative exact
// fp32 dots (2-cand ILP) -> tie-corrected threshold -> mask + deg^-0.5.
// v0 (S16 row) and ai (own x row) are PRELOADED by the caller.
// ---------------------------------------------------------------------------
__device__ __forceinline__ void thresh_row(const float (&v0)[8], const float4 (&ai)[4],
                                           int row, int lane,
                                           const float* __restrict__ x,
                                           unsigned long long* __restrict__ masks,
                                           float* __restrict__ dinv) {
    const int bb_ = row >> 9, ii = row & (N - 1);

    // sigma-based bracket estimate (diagonal excluded)
    float sum2 = 0.f;
#pragma unroll
    for (int k = 0; k < 8; k++) {
        const float v = ((lane + 64 * k) == ii) ? 0.f : v0[k];
        sum2 = fmaf(v, v, sum2);
    }
#pragma unroll
    for (int off = 32; off > 0; off >>= 1) sum2 += __shfl_xor(sum2, off);
    const float Pest = 1.542f * sqrtf(sum2 * (1.0f / 511.0f));
    const float bhi = Pest + 10.f, blo = Pest - 10.f;
    int chk_hi = 0, chk_lo = 0;
#pragma unroll
    for (int k = 0; k < 8; k++) {
        chk_hi += __popcll(__ballot(v0[k] > bhi));
        chk_lo += __popcll(__ballot(v0[k] > blo));
    }

    // bisection: invariant cnt(lo) >= 32, cnt(hi) <= 31, cnt(p)=#{v>p}
    float lo, hi;
    int nit;
    if (chk_hi <= K_NEIGH - 1 && chk_lo >= K_NEIGH) {
        lo = blo; hi = bhi; nit = 5;                     // window 0.625
    } else {
        lo = -1400.f; hi = 1400.f; nit = BISECT_ITERS;   // window 0.684
    }
    for (int it = 0; it < nit; it++) {
        const float mid = 0.5f * (lo + hi);
        int c = 0;
#pragma unroll
        for (int k = 0; k < 8; k++) c += __popcll(__ballot(v0[k] > mid));
        if (c >= K_NEIGH) lo = mid; else hi = mid;
    }
    const float P   = 0.5f * (lo + hi);
    const float hiB = P + DELTA, loB = P - DELTA;

    int cA = 0;
#pragma unroll
    for (int k = 0; k < 8; k++) cA += __popcll(__ballot(v0[k] > hiB));
    const int m_need = K_NEIGH - cA;   // >= 1

    // band candidates: one per lane
    int cnt = 0, myj = -1;
#pragma unroll
    for (int kq = 0; kq < 8; kq++) {
        unsigned long long bm = __ballot(v0[kq] >= loB && v0[kq] <= hiB);
        while (bm) {
            int bl = __ffsll(bm) - 1;
            bm &= bm - 1;
            if (cnt == lane) myj = bl + 64 * kq;
            cnt++;
        }
    }
    const int nc = cnt < 64 ? cnt : 64;

    // wave-cooperative exact dots, 2 candidates per pass (per-candidate
    // fma/reduce order identical to the serial version -> same fp32 values)
    float ex = -INFINITY;
    for (int c2 = 0; c2 < nc; c2 += 2) {
        const int c3 = (c2 + 1 < nc) ? c2 + 1 : c2;
        const int j0 = __shfl(myj, c2);
        const int j1 = __shfl(myj, c3);
        const float* xj0 = x + ((size_t)bb_ * N + j0) * C;
        const float* xj1 = x + ((size_t)bb_ * N + j1) * C;
        float s0 = 0.f, s1 = 0.f;
#pragma unroll
        for (int q = 0; q < 4; q++) {
            float4 b0 = *(const float4*)(xj0 + q * 256 + lane * 4);
            float4 b1 = *(const float4*)(xj1 + q * 256 + lane * 4);
            s0 = fmaf(ai[q].x, b0.x, s0);
            s0 = fmaf(ai[q].y, b0.y, s0);
            s0 = fmaf(ai[q].z, b0.z, s0);
            s0 = fmaf(ai[q].w, b0.w, s0);
            s1 = fmaf(ai[q].x, b1.x, s1);
            s1 = fmaf(ai[q].y, b1.y, s1);
            s1 = fmaf(ai[q].z, b1.z, s1);
            s1 = fmaf(ai[q].w, b1.w, s1);
        }
#pragma unroll
        for (int off = 32; off > 0; off >>= 1) {
            s0 += __shfl_xor(s0, off);
            s1 += __shfl_xor(s1, off);
        }
        if (lane == c2) ex = s0;
        if (lane == c3 && c3 != c2) ex = s1;
    }

    // exact threshold T = m_need-th largest band value (tie-correct)
    float val = ex, T = -INFINITY;
    for (int it = 0; it < m_need; it++) {
        float M = val;
#pragma unroll
        for (int off = 32; off > 0; off >>= 1) M = fmaxf(M, __shfl_xor(M, off));
        T = M;
        unsigned long long ball = __ballot(val == M);
        int first = __ffsll(ball) - 1;
        if (lane == first) val = -INFINITY;
    }
    const int dec = (lane < nc && ex >= T) ? 1 : 0;

    // adjacency bits: certain-above -> 1, band -> exact decision, else 0
    int bits[8];
#pragma unroll
    for (int kq = 0; kq < 8; kq++) bits[kq] = (v0[kq] > hiB) ? 1 : 0;
    for (int c2 = 0; c2 < nc; c2++) {
        int j = __shfl(myj, c2);
        int d = __shfl(dec, c2);
        if ((j & 63) == lane) bits[j >> 6] = d;
    }

    unsigned long long msk[8];
    int deg = 0;
#pragma unroll
    for (int kq = 0; kq < 8; kq++) {
        msk[kq] = __ballot(bits[kq] != 0);
        deg += __popcll(msk[kq]);
    }
    if (lane == 0) {
#pragma unroll
        for (int kq = 0; kq < 8; kq++) masks[(size_t)row * 8 + kq] = msk[kq];
        dinv[row] = rsqrtf((float)deg);
    }
}

// ---------------------------------------------------------------------------
// Kernel 2: TWO rows per wave. thresh is HBM-stream-bound (compulsory
// S16 33.5MB + x 128MB ~ 161MB; at ~3.3 TB/s mixed-chain rate = the observed
// ~50us -- r7's VALU halving was null, confirming the regime). Lever: MLP.
// Both rows' v0 (16 loads) + ai (8 float4) are hoisted into one 24-load
// burst before any compute; row1's consumption is ~2000cy after issue.
// State statically named (no runtime-indexed arrays -> no scratch).
// 4096 blocks x 4 waves x 2 rows = 32768 rows. XCD swizzle as before.
// ---------------------------------------------------------------------------
__global__ __launch_bounds__(256) void thresh_mask(const _Float16* __restrict__ S16,
                                                   const float* __restrict__ x,
                                                   unsigned long long* __restrict__ masks,
                                                   float* __restrict__ dinv) {
    const int id   = blockIdx.x;               // 0..4095
    const int xcd  = id & 7;
    const int slot = id >> 3;                  // 0..511
    const int bsw  = xcd * 8 + (slot >> 6);    // batch (8 per XCD)
    const int rblk = slot & 63;                // 8-row block within batch
    const int lane = threadIdx.x & 63;
    const int row0 = bsw * N + rblk * 8 + (threadIdx.x >> 6) * 2;
    const int row1 = row0 + 1;

    const _Float16* S0 = S16 + (size_t)row0 * N;
    const _Float16* S1 = S16 + (size_t)row1 * N;
    const float* xi0 = x + (size_t)row0 * C;
    const float* xi1 = x + (size_t)row1 * C;

    // ---- hoisted load burst: 24 independent loads in flight ----
    float v0a[8], v0b[8];
#pragma unroll
    for (int k = 0; k < 8; k++) v0a[k] = (float)S0[lane + 64 * k];
#pragma unroll
    for (int k = 0; k < 8; k++) v0b[k] = (float)S1[lane + 64 * k];
    float4 ai0[4], ai1[4];
#pragma unroll
    for (int q = 0; q < 4; q++) ai0[q] = *(const float4*)(xi0 + q * 256 + lane * 4);
#pragma unroll
    for (int q = 0; q < 4; q++) ai1[q] = *(const float4*)(xi1 + q * 256 + lane * 4);

    thresh_row(v0a, ai0, row0, lane, x, masks, dinv);
    thresh_row(v0b, ai1, row1, lane, x, masks, dinv);
}

// ---------------------------------------------------------------------------
// Kernel 3: out[b,i,j] = maskbit ? dinv[b,i]*dinv[b,j] : 0
// ---------------------------------------------------------------------------
__global__ __launch_bounds__(256) void scale_adj(float* __restrict__ Sout,
                                                 const unsigned long long* __restrict__ masks,
                                                 const float* __restrict__ dinv) {
    const int idx = blockIdx.x * 256 + threadIdx.x;   // float4 index
    const int jq = idx & 127;
    const int i  = (idx >> 7) & (N - 1);
    const int b  = idx >> 16;
    const int row = (b << 9) | i;
    const int j0 = jq * 4;

    const unsigned long long mk = masks[(size_t)row * 8 + (j0 >> 6)];
    const float di = dinv[row];
    float4 dj = ((const float4*)dinv)[(b << 7) | jq];

    float4 o;
    o.x = ((mk >> ((j0 + 0) & 63)) & 1ull) ? di * dj.x : 0.f;
    o.y = ((mk >> ((j0 + 1) & 63)) & 1ull) ? di * dj.y : 0.f;
    o.z = ((mk >> ((j0 + 2) & 63)) & 1ull) ? di * dj.z : 0.f;
    o.w = ((mk >> ((j0 + 3) & 63)) & 1ull) ? di * dj.w : 0.f;
    ((float4*)Sout)[idx] = o;
}

// ---------------------------------------------------------------------------
extern "C" void kernel_launch(void* const* d_in, const int* in_sizes, int n_in,
                              void* d_out, int out_size, void* d_ws, size_t ws_size,
                              hipStream_t stream) {
    const float* x = (const float*)d_in[0];
    float* out = (float*)d_out;                      // final fp32 output
    _Float16* S16 = (_Float16*)d_out;                // staged fp16 S' (first 33.5MB)
    unsigned long long* masks = (unsigned long long*)d_ws;     // B*N*8 u64 = 2MB
    float* dinv = (float*)(masks + (size_t)B * N * 8);         // B*N floats

    gemm_f16<<<dim3(B * 4), 512, 0, stream>>>(x, S16);         // 256 blocks = 1/CU
    thresh_mask<<<B * N / 8, 256, 0, stream>>>(S16, x, masks, dinv);
    const int total4 = B * N * N / 4;
    scale_adj<<<total4 / 256, 256, 0, stream>>>(out, masks, dinv);
}